// Round 2
// baseline (4720.901 us; speedup 1.0000x reference)
//
#include <hip/hip_runtime.h>
#include <hip/hip_bf16.h>
#include <hip/hip_fp16.h>

#define T_ 512
#define B_ 128
#define E_ 256
#define H_ 256
#define NW 16   // workgroups per direction in the recurrence kernel

typedef _Float16 h8 __attribute__((ext_vector_type(8)));
typedef float    f4 __attribute__((ext_vector_type(4)));

// ---------------------------------------------------------------------------
// K1: embedding gather + fp32->fp16, written in MFMA A-fragment order:
// frag(t, mt, kb) element addr = ((t*64 + mt*8 + kb)*64 + lane)*8 halves,
// holding x[t][b = mt*16 + (lane&15)][e = kb*32 + (lane>>4)*8 + j], j=0..7
// ---------------------------------------------------------------------------
__global__ __launch_bounds__(256) void k_gather(const int* __restrict__ tok,
        const float* __restrict__ emb, _Float16* __restrict__ x16)
{
    const int t = blockIdx.x;
    const int tid = threadIdx.x;
    const int wave = tid >> 6, lane = tid & 63;
    const int q = lane >> 4, l16 = lane & 15;
    __shared__ int rows[B_];
    if (tid < B_) rows[tid] = tok[(size_t)tid * T_ + t];
    __syncthreads();
    for (int it = 0; it < 16; ++it) {
        int pair = it * 4 + wave;          // pair = mt*8 + kb
        int mt = pair >> 3, kb = pair & 7;
        int b = mt * 16 + l16;
        int e = kb * 32 + q * 8;
        const float* src = emb + (size_t)rows[b] * E_ + e;
        float4 a = *(const float4*)src;
        float4 c = *(const float4*)(src + 4);
        h8 hv;
        hv[0]=(_Float16)a.x; hv[1]=(_Float16)a.y; hv[2]=(_Float16)a.z; hv[3]=(_Float16)a.w;
        hv[4]=(_Float16)c.x; hv[5]=(_Float16)c.y; hv[6]=(_Float16)c.z; hv[7]=(_Float16)c.w;
        *(h8*)(x16 + (((size_t)t * 64 + pair) * 64 + lane) * 8) = hv;
    }
}

// ---------------------------------------------------------------------------
// K2: weight permute+convert. Output Wp[d][w][n][k]: n in [0,64) = gate*16+jl,
// k in [0,512): k<256 -> W[k][col], k>=256 -> U[k-256][col], col = g*256+w*16+jl.
// fp16, n-major so K3's per-lane 16B B-fragment loads are contiguous in k.
// ---------------------------------------------------------------------------
__global__ __launch_bounds__(256) void k_wperm(const float* __restrict__ Wf, const float* __restrict__ Uf,
        const float* __restrict__ Wb, const float* __restrict__ Ub, _Float16* __restrict__ wp)
{
    const int wg = blockIdx.x;           // 0..31
    const int d = wg >> 4, w = wg & 15;
    const int tid = threadIdx.x;
    const float* W = d ? Wb : Wf;
    const float* U = d ? Ub : Uf;
    __shared__ _Float16 S[256][66];      // padded to break bank alignment
    _Float16* out = wp + (size_t)wg * 64 * 512;
    for (int half = 0; half < 2; ++half) {
        const float* src = half ? U : W;
        for (int it = 0; it < 64; ++it) {
            int idx = it * 256 + tid;
            int k = idx >> 6, n = idx & 63;
            int g = n >> 4, jl = n & 15;
            int col = g * 256 + w * 16 + jl;
            S[k][n] = (_Float16)src[(size_t)k * 1024 + col];
        }
        __syncthreads();
        for (int it = 0; it < 64; ++it) {
            int idx = it * 256 + tid;
            int n = idx >> 8, k = idx & 255;
            out[n * 512 + half * 256 + k] = S[k][n];
        }
        __syncthreads();
    }
}

// ---------------------------------------------------------------------------
// K3: persistent bidirectional LSTM recurrence. 32 blocks (16 per direction),
// 256 threads, 1 block/CU, 1 wave/SIMD (amdgpu_waves_per_eu(1,1) grants the
// full 512-VGPR budget so the [512x64] fp16 weight slice stays VGPR-resident).
// WG w owns hidden units j = w*16 .. w*16+15 (64 gate columns). Per-direction
// flag barrier each step; H broadcast via double-buffered global fp16 buffer.
// ---------------------------------------------------------------------------
__device__ __forceinline__ float fsig(float x) {
    float t = __expf(-fabsf(x));
    float r = __builtin_amdgcn_rcpf(1.0f + t);
    return x >= 0.f ? r : 1.0f - r;
}
__device__ __forceinline__ float ftanh(float x) {
    float t = __expf(-2.0f * fabsf(x));
    float r = (1.0f - t) * __builtin_amdgcn_rcpf(1.0f + t);
    return x >= 0.f ? r : -r;
}

__global__ __launch_bounds__(256, 1) __attribute__((amdgpu_waves_per_eu(1, 1)))
void k_rnn(const _Float16* __restrict__ x16,
        const _Float16* __restrict__ wp, const float* __restrict__ bf, const float* __restrict__ bb,
        _Float16* __restrict__ hbuf, float* __restrict__ hfin, unsigned int* __restrict__ flags)
{
    const int wg = blockIdx.x;
    const int d = wg >> 4, w = wg & 15;
    const int tid = threadIdx.x;
    const int wave = tid >> 6, lane = tid & 63;
    const int q = lane >> 4, l16 = lane & 15;

    // persistent weight fragments: wx = x-part (k 0..255), wu = h-part (k 256..511)
    h8 wx[4][8], wu[4][8];
    {
        const h8* base = (const h8*)(wp + (size_t)wg * 64 * 512);
        #pragma unroll
        for (int nt = 0; nt < 4; ++nt)
            #pragma unroll
            for (int kb = 0; kb < 8; ++kb) {
                wx[nt][kb] = base[(nt * 16 + l16) * 64 + kb * 4 + q];
                wu[nt][kb] = base[(nt * 16 + l16) * 64 + (kb + 8) * 4 + q];
            }
    }
    const float* bias = d ? bb : bf;
    const float bs0 = bias[0 * 256 + w * 16 + l16];
    const float bs1 = bias[1 * 256 + w * 16 + l16];
    const float bs2 = bias[2 * 256 + w * 16 + l16];
    const float bs3 = bias[3 * 256 + w * 16 + l16];

    unsigned int* myflags = flags + d * 32;

    float c[2][4];
    float hv[2][4];
    #pragma unroll
    for (int mt = 0; mt < 2; ++mt)
        #pragma unroll
        for (int r = 0; r < 4; ++r) { c[mt][r] = 0.f; hv[mt][r] = 0.f; }

    // prefetch x fragments for step 0
    h8 xf[2][8];
    {
        int xt = d ? (T_ - 1) : 0;
        const h8* xb = (const h8*)x16 + ((size_t)xt * 64 + (size_t)(wave * 2) * 8) * 64 + lane;
        #pragma unroll
        for (int mt = 0; mt < 2; ++mt)
            #pragma unroll
            for (int kb = 0; kb < 8; ++kb)
                xf[mt][kb] = xb[(mt * 8 + kb) * 64];
    }

    f4 acc[2][4];

    for (int s = 0; s < T_; ++s) {
        if (s > 0) {
            // wait for all 16 WGs of this direction to publish h_s
            if (tid < NW) {
                while (__hip_atomic_load(&myflags[tid], __ATOMIC_RELAXED, __HIP_MEMORY_SCOPE_AGENT) < (unsigned)s)
                    __builtin_amdgcn_s_sleep(1);
            }
            __syncthreads();
            __builtin_amdgcn_fence(__ATOMIC_ACQUIRE, "agent");
            // H fragments, direct from global (LLC) — issue all loads first
            h8 hf[2][8];
            {
                const h8* hb = (const h8*)(hbuf + (size_t)((s & 1) * 2 + d) * B_ * H_);
                #pragma unroll
                for (int mt = 0; mt < 2; ++mt) {
                    int b = (wave * 2 + mt) * 16 + l16;
                    #pragma unroll
                    for (int kb = 0; kb < 8; ++kb)
                        hf[mt][kb] = hb[b * 32 + kb * 4 + q];
                }
            }
            // x-part (fragments prefetched last iteration; overlaps hf latency)
            #pragma unroll
            for (int mt = 0; mt < 2; ++mt)
                #pragma unroll
                for (int nt = 0; nt < 4; ++nt) {
                    f4 a = {0.f, 0.f, 0.f, 0.f};
                    #pragma unroll
                    for (int kb = 0; kb < 8; ++kb)
                        a = __builtin_amdgcn_mfma_f32_16x16x32_f16(xf[mt][kb], wx[nt][kb], a, 0, 0, 0);
                    acc[mt][nt] = a;
                }
            // h-part
            #pragma unroll
            for (int kb = 0; kb < 8; ++kb)
                #pragma unroll
                for (int mt = 0; mt < 2; ++mt)
                    #pragma unroll
                    for (int nt = 0; nt < 4; ++nt)
                        acc[mt][nt] = __builtin_amdgcn_mfma_f32_16x16x32_f16(hf[mt][kb], wu[nt][kb], acc[mt][nt], 0, 0, 0);
        } else {
            #pragma unroll
            for (int mt = 0; mt < 2; ++mt)
                #pragma unroll
                for (int nt = 0; nt < 4; ++nt) {
                    f4 a = {0.f, 0.f, 0.f, 0.f};
                    #pragma unroll
                    for (int kb = 0; kb < 8; ++kb)
                        a = __builtin_amdgcn_mfma_f32_16x16x32_f16(xf[mt][kb], wx[nt][kb], a, 0, 0, 0);
                    acc[mt][nt] = a;
                }
        }
        // gates (fp32), update c, emit h
        {
            _Float16* hout = hbuf + (size_t)(((s + 1) & 1) * 2 + d) * B_ * H_;
            #pragma unroll
            for (int mt = 0; mt < 2; ++mt)
                #pragma unroll
                for (int r = 0; r < 4; ++r) {
                    float zi = acc[mt][0][r] + bs0;
                    float zf = acc[mt][1][r] + bs1;
                    float zg = acc[mt][2][r] + bs2;
                    float zo = acc[mt][3][r] + bs3;
                    float cn = fsig(zf) * c[mt][r] + fsig(zi) * ftanh(zg);
                    c[mt][r] = cn;
                    float hh = fsig(zo) * ftanh(cn);
                    hv[mt][r] = hh;
                    if (s < T_ - 1) {
                        int b = (wave * 2 + mt) * 16 + q * 4 + r;
                        hout[b * H_ + w * 16 + l16] = (_Float16)hh;
                    }
                }
        }
        if (s < T_ - 1) {
            __builtin_amdgcn_fence(__ATOMIC_RELEASE, "agent");
            __syncthreads();
            if (tid == 0)
                __hip_atomic_store(&myflags[w], (unsigned)(s + 1), __ATOMIC_RELAXED, __HIP_MEMORY_SCOPE_AGENT);
            // prefetch next step's x fragments; in flight during the spin
            int xt = d ? (T_ - 2 - s) : (s + 1);
            const h8* xb = (const h8*)x16 + ((size_t)xt * 64 + (size_t)(wave * 2) * 8) * 64 + lane;
            #pragma unroll
            for (int mt = 0; mt < 2; ++mt)
                #pragma unroll
                for (int kb = 0; kb < 8; ++kb)
                    xf[mt][kb] = xb[(mt * 8 + kb) * 64];
        }
    }
    // final h -> hfin (fp32)
    #pragma unroll
    for (int mt = 0; mt < 2; ++mt)
        #pragma unroll
        for (int r = 0; r < 4; ++r) {
            int b = (wave * 2 + mt) * 16 + q * 4 + r;
            hfin[((size_t)d * B_ + b) * H_ + w * 16 + l16] = hv[mt][r];
        }
}

// ---------------------------------------------------------------------------
// K4: head. One block per batch row: a1 = relu([h_fwd|h_bwd] @ W1 + b1),
// logits = a1 @ W2 + b2, softmax over 32 classes. All fp32.
// ---------------------------------------------------------------------------
__global__ __launch_bounds__(256) void k_head(const float* __restrict__ hfin,
        const float* __restrict__ W1, const float* __restrict__ b1,
        const float* __restrict__ W2, const float* __restrict__ b2, float* __restrict__ out)
{
    const int b = blockIdx.x;
    const int tid = threadIdx.x;
    __shared__ float hcat[2 * H_];
    __shared__ float a1[256];
    if (tid < 128) {
        if (tid < 64)
            ((float4*)hcat)[tid] = ((const float4*)(hfin + (size_t)b * H_))[tid];
        else
            ((float4*)(hcat + H_))[tid - 64] = ((const float4*)(hfin + (size_t)(B_ + b) * H_))[tid - 64];
    }
    __syncthreads();
    {
        float s = b1[tid];
        #pragma unroll 4
        for (int k = 0; k < 2 * H_; ++k)
            s += hcat[k] * W1[(size_t)k * 256 + tid];
        a1[tid] = s > 0.f ? s : 0.f;
    }
    __syncthreads();
    if (tid < 32) {
        float s = b2[tid];
        #pragma unroll 4
        for (int j = 0; j < 256; ++j)
            s += a1[j] * W2[(size_t)j * 32 + tid];
        float mx = s;
        #pragma unroll
        for (int o = 16; o > 0; o >>= 1)
            mx = fmaxf(mx, __shfl_xor(mx, o, 32));
        float e = __expf(s - mx);
        float sum = e;
        #pragma unroll
        for (int o = 16; o > 0; o >>= 1)
            sum += __shfl_xor(sum, o, 32);
        out[(size_t)b * 32 + tid] = e / sum;
    }
}

// ---------------------------------------------------------------------------
extern "C" void kernel_launch(void* const* d_in, const int* in_sizes, int n_in,
                              void* d_out, int out_size, void* d_ws, size_t ws_size,
                              hipStream_t stream)
{
    (void)in_sizes; (void)n_in; (void)out_size; (void)ws_size;
    const int*   tok = (const int*)d_in[0];
    const float* emb = (const float*)d_in[1];
    const float* Wf  = (const float*)d_in[2];
    const float* Uf  = (const float*)d_in[3];
    const float* bf  = (const float*)d_in[4];
    const float* Wb  = (const float*)d_in[5];
    const float* Ub  = (const float*)d_in[6];
    const float* bb  = (const float*)d_in[7];
    const float* W1  = (const float*)d_in[8];
    const float* b1  = (const float*)d_in[9];
    const float* W2  = (const float*)d_in[10];
    const float* b2  = (const float*)d_in[11];
    float* out = (float*)d_out;

    char* ws = (char*)d_ws;
    _Float16* x16   = (_Float16*)(ws);                 // 33,554,432 B  frag-ordered x
    _Float16* wp    = (_Float16*)(ws + 33554432);      //  2,097,152 B  permuted weights
    _Float16* hbuf  = (_Float16*)(ws + 35651584);      //    262,144 B  H double buffer [2][2][128][256]
    float*    hfin  = (float*)   (ws + 35913728);      //    262,144 B  final h fp32 [2][128][256]
    unsigned* flags = (unsigned*)(ws + 36175872);      //        512 B  barrier flags

    hipMemsetAsync(flags, 0, 512, stream);
    k_gather<<<T_, 256, 0, stream>>>(tok, emb, x16);
    k_wperm <<<32,  256, 0, stream>>>(Wf, Uf, Wb, Ub, wp);
    k_rnn   <<<32,  256, 0, stream>>>(x16, wp, bf, bb, hbuf, hfin, flags);
    k_head  <<<B_,  256, 0, stream>>>(hfin, W1, b1, W2, b2, out);
}

// Round 3
// 2813.354 us; speedup vs baseline: 1.6780x; 1.6780x over previous
//
#include <hip/hip_runtime.h>
#include <hip/hip_bf16.h>
#include <hip/hip_fp16.h>

#define T_ 512
#define B_ 128
#define E_ 256
#define H_ 256
#define NW 16   // workgroups per direction in the recurrence kernel

typedef _Float16 h8 __attribute__((ext_vector_type(8)));
typedef float    f4 __attribute__((ext_vector_type(4)));

// ---------------------------------------------------------------------------
// K1: embedding gather + fp32->fp16, written in MFMA A-fragment order:
// frag(t, mt, kb) element addr = ((t*64 + mt*8 + kb)*64 + lane)*8 halves,
// holding x[t][b = mt*16 + (lane&15)][e = kb*32 + (lane>>4)*8 + j], j=0..7
// ---------------------------------------------------------------------------
__global__ __launch_bounds__(256) void k_gather(const int* __restrict__ tok,
        const float* __restrict__ emb, _Float16* __restrict__ x16)
{
    const int t = blockIdx.x;
    const int tid = threadIdx.x;
    const int wave = tid >> 6, lane = tid & 63;
    const int q = lane >> 4, l16 = lane & 15;
    __shared__ int rows[B_];
    if (tid < B_) rows[tid] = tok[(size_t)tid * T_ + t];
    __syncthreads();
    for (int it = 0; it < 16; ++it) {
        int pair = it * 4 + wave;          // pair = mt*8 + kb
        int mt = pair >> 3, kb = pair & 7;
        int b = mt * 16 + l16;
        int e = kb * 32 + q * 8;
        const float* src = emb + (size_t)rows[b] * E_ + e;
        float4 a = *(const float4*)src;
        float4 c = *(const float4*)(src + 4);
        h8 hv;
        hv[0]=(_Float16)a.x; hv[1]=(_Float16)a.y; hv[2]=(_Float16)a.z; hv[3]=(_Float16)a.w;
        hv[4]=(_Float16)c.x; hv[5]=(_Float16)c.y; hv[6]=(_Float16)c.z; hv[7]=(_Float16)c.w;
        *(h8*)(x16 + (((size_t)t * 64 + pair) * 64 + lane) * 8) = hv;
    }
}

// ---------------------------------------------------------------------------
// K2: weight permute+convert. Output Wp[d][w][n][k]: n in [0,64) = gate*16+jl,
// k in [0,512): k<256 -> W[k][col], k>=256 -> U[k-256][col], col = g*256+w*16+jl.
// fp16, n-major so K3's per-lane 16B B-fragment loads are contiguous in k.
// ---------------------------------------------------------------------------
__global__ __launch_bounds__(256) void k_wperm(const float* __restrict__ Wf, const float* __restrict__ Uf,
        const float* __restrict__ Wb, const float* __restrict__ Ub, _Float16* __restrict__ wp)
{
    const int wg = blockIdx.x;           // 0..31
    const int d = wg >> 4, w = wg & 15;
    const int tid = threadIdx.x;
    const float* W = d ? Wb : Wf;
    const float* U = d ? Ub : Uf;
    __shared__ _Float16 S[256][66];      // padded to break bank alignment
    _Float16* out = wp + (size_t)wg * 64 * 512;
    for (int half = 0; half < 2; ++half) {
        const float* src = half ? U : W;
        for (int it = 0; it < 64; ++it) {
            int idx = it * 256 + tid;
            int k = idx >> 6, n = idx & 63;
            int g = n >> 4, jl = n & 15;
            int col = g * 256 + w * 16 + jl;
            S[k][n] = (_Float16)src[(size_t)k * 1024 + col];
        }
        __syncthreads();
        for (int it = 0; it < 64; ++it) {
            int idx = it * 256 + tid;
            int n = idx >> 8, k = idx & 255;
            out[n * 512 + half * 256 + k] = S[k][n];
        }
        __syncthreads();
    }
}

// ---------------------------------------------------------------------------
// K3: persistent bidirectional LSTM recurrence. 32 blocks (16 per direction),
// 256 threads. WG w owns hidden units j = w*16..w*16+15 (64 gate columns);
// [512x64] fp16 weight slice operand-resident in the unified VGPR/AGPR file.
// Cross-WG H broadcast goes DIRECTLY through the LLC via sc0+sc1 loads/stores
// (no agent fences -> no per-step buffer_wbl2/buffer_inv L2 maintenance).
// Per-direction monotonic flag barrier each step; H double-buffered in global.
// ---------------------------------------------------------------------------
__device__ __forceinline__ float fsig(float x) {
    float t = __expf(-fabsf(x));
    float r = __builtin_amdgcn_rcpf(1.0f + t);
    return x >= 0.f ? r : 1.0f - r;
}
__device__ __forceinline__ float ftanh(float x) {
    float t = __expf(-2.0f * fabsf(x));
    float r = (1.0f - t) * __builtin_amdgcn_rcpf(1.0f + t);
    return x >= 0.f ? r : -r;
}

// 16B load straight from the coherence point (bypass L1+L2). No waitcnt here;
// caller must drain vmcnt before using the result.
__device__ __forceinline__ void llc_load16(h8* dst, const _Float16* p) {
    asm volatile("global_load_dwordx4 %0, %1, off sc0 sc1"
                 : "=v"(*dst) : "v"(p) : "memory");
}
// 2B write-through to the coherence point.
__device__ __forceinline__ void llc_store2(_Float16* p, unsigned v) {
    asm volatile("global_store_short %0, %1, off sc0 sc1"
                 :: "v"(p), "v"(v) : "memory");
}

__global__ __launch_bounds__(256, 1) __attribute__((amdgpu_waves_per_eu(1, 1)))
void k_rnn(const _Float16* __restrict__ x16,
        const _Float16* __restrict__ wp, const float* __restrict__ bf, const float* __restrict__ bb,
        _Float16* __restrict__ hbuf, float* __restrict__ hfin, unsigned int* __restrict__ flags)
{
    const int wg = blockIdx.x;
    const int d = wg >> 4, w = wg & 15;
    const int tid = threadIdx.x;
    const int wave = tid >> 6, lane = tid & 63;
    const int q = lane >> 4, l16 = lane & 15;

    // persistent weight fragments: wx = x-part (k 0..255), wu = h-part (k 256..511)
    h8 wx[4][8], wu[4][8];
    {
        const h8* base = (const h8*)(wp + (size_t)wg * 64 * 512);
        #pragma unroll
        for (int nt = 0; nt < 4; ++nt)
            #pragma unroll
            for (int kb = 0; kb < 8; ++kb) {
                wx[nt][kb] = base[(nt * 16 + l16) * 64 + kb * 4 + q];
                wu[nt][kb] = base[(nt * 16 + l16) * 64 + (kb + 8) * 4 + q];
            }
    }
    const float* bias = d ? bb : bf;
    const float bs0 = bias[0 * 256 + w * 16 + l16];
    const float bs1 = bias[1 * 256 + w * 16 + l16];
    const float bs2 = bias[2 * 256 + w * 16 + l16];
    const float bs3 = bias[3 * 256 + w * 16 + l16];

    unsigned int* myflags = flags + d * 32;

    float c[2][4];
    float hv[2][4];
    #pragma unroll
    for (int mt = 0; mt < 2; ++mt)
        #pragma unroll
        for (int r = 0; r < 4; ++r) { c[mt][r] = 0.f; hv[mt][r] = 0.f; }

    // prefetch x fragments for step 0 (plain cached loads; x16 is read-only)
    h8 xf[2][8];
    {
        int xt = d ? (T_ - 1) : 0;
        const h8* xb = (const h8*)x16 + ((size_t)xt * 64 + (size_t)(wave * 2) * 8) * 64 + lane;
        #pragma unroll
        for (int mt = 0; mt < 2; ++mt)
            #pragma unroll
            for (int kb = 0; kb < 8; ++kb)
                xf[mt][kb] = xb[(mt * 8 + kb) * 64];
    }

    f4 acc[2][4];

    for (int s = 0; s < T_; ++s) {
        if (s > 0) {
            // wait for all 16 WGs of this direction to publish h_s
            if (tid < NW) {
                while (__hip_atomic_load(&myflags[tid], __ATOMIC_RELAXED, __HIP_MEMORY_SCOPE_AGENT) < (unsigned)s)
                    __builtin_amdgcn_s_sleep(1);
            }
            __syncthreads();
            // issue all 16 H-fragment loads from the LLC
            h8 hf[2][8];
            {
                const _Float16* hb = hbuf + (size_t)((s & 1) * 2 + d) * B_ * H_;
                #pragma unroll
                for (int mt = 0; mt < 2; ++mt) {
                    int b = (wave * 2 + mt) * 16 + l16;
                    #pragma unroll
                    for (int kb = 0; kb < 8; ++kb)
                        llc_load16(&hf[mt][kb], hb + (size_t)b * H_ + kb * 32 + q * 8);
                }
            }
            // x-part MFMAs overlap the H-load latency (independent of hf)
            #pragma unroll
            for (int mt = 0; mt < 2; ++mt)
                #pragma unroll
                for (int nt = 0; nt < 4; ++nt) {
                    f4 a = {0.f, 0.f, 0.f, 0.f};
                    #pragma unroll
                    for (int kb = 0; kb < 8; ++kb)
                        a = __builtin_amdgcn_mfma_f32_16x16x32_f16(xf[mt][kb], wx[nt][kb], a, 0, 0, 0);
                    acc[mt][nt] = a;
                }
            // drain the H loads; tying hf as in/outs forces h-MFMAs after this
            asm volatile("s_waitcnt vmcnt(0)"
                : "+v"(hf[0][0]), "+v"(hf[0][1]), "+v"(hf[0][2]), "+v"(hf[0][3]),
                  "+v"(hf[0][4]), "+v"(hf[0][5]), "+v"(hf[0][6]), "+v"(hf[0][7]),
                  "+v"(hf[1][0]), "+v"(hf[1][1]), "+v"(hf[1][2]), "+v"(hf[1][3]),
                  "+v"(hf[1][4]), "+v"(hf[1][5]), "+v"(hf[1][6]), "+v"(hf[1][7])
                :: "memory");
            // h-part
            #pragma unroll
            for (int kb = 0; kb < 8; ++kb)
                #pragma unroll
                for (int mt = 0; mt < 2; ++mt)
                    #pragma unroll
                    for (int nt = 0; nt < 4; ++nt)
                        acc[mt][nt] = __builtin_amdgcn_mfma_f32_16x16x32_f16(hf[mt][kb], wu[nt][kb], acc[mt][nt], 0, 0, 0);
        } else {
            #pragma unroll
            for (int mt = 0; mt < 2; ++mt)
                #pragma unroll
                for (int nt = 0; nt < 4; ++nt) {
                    f4 a = {0.f, 0.f, 0.f, 0.f};
                    #pragma unroll
                    for (int kb = 0; kb < 8; ++kb)
                        a = __builtin_amdgcn_mfma_f32_16x16x32_f16(xf[mt][kb], wx[nt][kb], a, 0, 0, 0);
                    acc[mt][nt] = a;
                }
        }
        // gates (fp32), update c, emit h straight to the LLC
        {
            _Float16* hout = hbuf + (size_t)(((s + 1) & 1) * 2 + d) * B_ * H_;
            #pragma unroll
            for (int mt = 0; mt < 2; ++mt)
                #pragma unroll
                for (int r = 0; r < 4; ++r) {
                    float zi = acc[mt][0][r] + bs0;
                    float zf = acc[mt][1][r] + bs1;
                    float zg = acc[mt][2][r] + bs2;
                    float zo = acc[mt][3][r] + bs3;
                    float cn = fsig(zf) * c[mt][r] + fsig(zi) * ftanh(zg);
                    c[mt][r] = cn;
                    float hh = fsig(zo) * ftanh(cn);
                    hv[mt][r] = hh;
                    if (s < T_ - 1) {
                        int b = (wave * 2 + mt) * 16 + q * 4 + r;
                        _Float16 hx = (_Float16)hh;
                        llc_store2(hout + (size_t)b * H_ + w * 16 + l16,
                                   (unsigned)__builtin_bit_cast(unsigned short, hx));
                    }
                }
        }
        if (s < T_ - 1) {
            // drain this wave's h stores to the LLC, rendezvous, publish
            asm volatile("s_waitcnt vmcnt(0)" ::: "memory");
            __syncthreads();
            if (tid == 0)
                __hip_atomic_store(&myflags[w], (unsigned)(s + 1), __ATOMIC_RELAXED, __HIP_MEMORY_SCOPE_AGENT);
            // prefetch next step's x fragments; in flight during the spin
            int xt = d ? (T_ - 2 - s) : (s + 1);
            const h8* xb = (const h8*)x16 + ((size_t)xt * 64 + (size_t)(wave * 2) * 8) * 64 + lane;
            #pragma unroll
            for (int mt = 0; mt < 2; ++mt)
                #pragma unroll
                for (int kb = 0; kb < 8; ++kb)
                    xf[mt][kb] = xb[(mt * 8 + kb) * 64];
        }
    }
    // final h -> hfin (fp32); kernel-end implicit release makes it visible
    #pragma unroll
    for (int mt = 0; mt < 2; ++mt)
        #pragma unroll
        for (int r = 0; r < 4; ++r) {
            int b = (wave * 2 + mt) * 16 + q * 4 + r;
            hfin[((size_t)d * B_ + b) * H_ + w * 16 + l16] = hv[mt][r];
        }
}

// ---------------------------------------------------------------------------
// K4: head. One block per batch row: a1 = relu([h_fwd|h_bwd] @ W1 + b1),
// logits = a1 @ W2 + b2, softmax over 32 classes. All fp32.
// ---------------------------------------------------------------------------
__global__ __launch_bounds__(256) void k_head(const float* __restrict__ hfin,
        const float* __restrict__ W1, const float* __restrict__ b1,
        const float* __restrict__ W2, const float* __restrict__ b2, float* __restrict__ out)
{
    const int b = blockIdx.x;
    const int tid = threadIdx.x;
    __shared__ float hcat[2 * H_];
    __shared__ float a1[256];
    if (tid < 128) {
        if (tid < 64)
            ((float4*)hcat)[tid] = ((const float4*)(hfin + (size_t)b * H_))[tid];
        else
            ((float4*)(hcat + H_))[tid - 64] = ((const float4*)(hfin + (size_t)(B_ + b) * H_))[tid - 64];
    }
    __syncthreads();
    {
        float s = b1[tid];
        #pragma unroll 4
        for (int k = 0; k < 2 * H_; ++k)
            s += hcat[k] * W1[(size_t)k * 256 + tid];
        a1[tid] = s > 0.f ? s : 0.f;
    }
    __syncthreads();
    if (tid < 32) {
        float s = b2[tid];
        #pragma unroll 4
        for (int j = 0; j < 256; ++j)
            s += a1[j] * W2[(size_t)j * 32 + tid];
        float mx = s;
        #pragma unroll
        for (int o = 16; o > 0; o >>= 1)
            mx = fmaxf(mx, __shfl_xor(mx, o, 32));
        float e = __expf(s - mx);
        float sum = e;
        #pragma unroll
        for (int o = 16; o > 0; o >>= 1)
            sum += __shfl_xor(sum, o, 32);
        out[(size_t)b * 32 + tid] = e / sum;
    }
}

// ---------------------------------------------------------------------------
extern "C" void kernel_launch(void* const* d_in, const int* in_sizes, int n_in,
                              void* d_out, int out_size, void* d_ws, size_t ws_size,
                              hipStream_t stream)
{
    (void)in_sizes; (void)n_in; (void)out_size; (void)ws_size;
    const int*   tok = (const int*)d_in[0];
    const float* emb = (const float*)d_in[1];
    const float* Wf  = (const float*)d_in[2];
    const float* Uf  = (const float*)d_in[3];
    const float* bf  = (const float*)d_in[4];
    const float* Wb  = (const float*)d_in[5];
    const float* Ub  = (const float*)d_in[6];
    const float* bb  = (const float*)d_in[7];
    const float* W1  = (const float*)d_in[8];
    const float* b1  = (const float*)d_in[9];
    const float* W2  = (const float*)d_in[10];
    const float* b2  = (const float*)d_in[11];
    float* out = (float*)d_out;

    char* ws = (char*)d_ws;
    _Float16* x16   = (_Float16*)(ws);                 // 33,554,432 B  frag-ordered x
    _Float16* wp    = (_Float16*)(ws + 33554432);      //  2,097,152 B  permuted weights
    _Float16* hbuf  = (_Float16*)(ws + 35651584);      //    262,144 B  H double buffer [2][2][128][256]
    float*    hfin  = (float*)   (ws + 35913728);      //    262,144 B  final h fp32 [2][128][256]
    unsigned* flags = (unsigned*)(ws + 36175872);      //        512 B  barrier flags

    hipMemsetAsync(flags, 0, 512, stream);
    k_gather<<<T_, 256, 0, stream>>>(tok, emb, x16);
    k_wperm <<<32,  256, 0, stream>>>(Wf, Uf, Wb, Ub, wp);
    k_rnn   <<<32,  256, 0, stream>>>(x16, wp, bf, bb, hbuf, hfin, flags);
    k_head  <<<B_,  256, 0, stream>>>(hfin, W1, b1, W2, b2, out);
}

// Round 6
// 2284.454 us; speedup vs baseline: 2.0665x; 1.2315x over previous
//
#include <hip/hip_runtime.h>
#include <hip/hip_bf16.h>
#include <hip/hip_fp16.h>

#define T_ 512
#define B_ 128
#define E_ 256
#define H_ 256

typedef _Float16 h8 __attribute__((ext_vector_type(8)));
typedef float    f4 __attribute__((ext_vector_type(4)));
typedef unsigned u4 __attribute__((ext_vector_type(4)));

// ---------------------------------------------------------------------------
// K1: embedding gather + fp32->fp16, MFMA A-fragment order:
// h8 index = (t*64 + grp*8 + kb)*64 + lane, holding
// x[t][b = grp*16 + (lane&15)][e = kb*32 + (lane>>4)*8 + j], j=0..7
// ---------------------------------------------------------------------------
__global__ __launch_bounds__(256) void k_gather(const int* __restrict__ tok,
        const float* __restrict__ emb, _Float16* __restrict__ x16)
{
    const int t = blockIdx.x;
    const int tid = threadIdx.x;
    const int wave = tid >> 6, lane = tid & 63;
    const int q = lane >> 4, l16 = lane & 15;
    __shared__ int rows[B_];
    if (tid < B_) rows[tid] = tok[(size_t)tid * T_ + t];
    __syncthreads();
    for (int it = 0; it < 16; ++it) {
        int pair = it * 4 + wave;          // pair = grp*8 + kb
        int grp = pair >> 3, kb = pair & 7;
        int b = grp * 16 + l16;
        int e = kb * 32 + q * 8;
        const float* src = emb + (size_t)rows[b] * E_ + e;
        float4 a = *(const float4*)src;
        float4 c = *(const float4*)(src + 4);
        h8 hv;
        hv[0]=(_Float16)a.x; hv[1]=(_Float16)a.y; hv[2]=(_Float16)a.z; hv[3]=(_Float16)a.w;
        hv[4]=(_Float16)c.x; hv[5]=(_Float16)c.y; hv[6]=(_Float16)c.z; hv[7]=(_Float16)c.w;
        *(h8*)(x16 + (((size_t)t * 64 + pair) * 64 + lane) * 8) = hv;
    }
}

// ---------------------------------------------------------------------------
// K2: weight permute+convert to fp16 B-fragment layout.
// wp element [(d*32 + mat*16 + p*4 + w)*16384 + nt*4096 + n*256 + k] =
//   M[k][nt*256 + p*64 + w*16 + n],  M = (mat? U : W) of direction d.
// One block per (d, mat, p, w) = 64 blocks.
// ---------------------------------------------------------------------------
__global__ __launch_bounds__(256) void k_perm(const float* __restrict__ Wf, const float* __restrict__ Uf,
        const float* __restrict__ Wb, const float* __restrict__ Ub, _Float16* __restrict__ wp)
{
    const int bid = blockIdx.x;
    const int d = bid >> 5, mat = (bid >> 4) & 1, p = (bid >> 2) & 3, w = bid & 3;
    const float* src = d ? (mat ? Ub : Wb) : (mat ? Uf : Wf);
    _Float16* dst = wp + (size_t)bid * 16384;
    const int tid = threadIdx.x;
    const int cbase = p * 64 + w * 16;
    __shared__ float S[256][17];
    for (int nt = 0; nt < 4; ++nt) {
        for (int it = 0; it < 16; ++it) {
            int idx = it * 256 + tid;
            int k = idx >> 4, c16 = idx & 15;
            S[k][c16] = src[(size_t)k * 1024 + nt * 256 + cbase + c16];
        }
        __syncthreads();
        for (int it = 0; it < 16; ++it) {
            int idx = it * 256 + tid;
            int k = idx & 255, c16 = idx >> 8;
            dst[(size_t)nt * 4096 + c16 * 256 + k] = (_Float16)S[k][c16];
        }
        __syncthreads();
    }
}

// ---------------------------------------------------------------------------
// K3: fused recurrence. 64 WGs = (d, p quarter of units, grp of 16 rows);
// wave w owns 16 units (4 gates x 16 cols) with the FULL K=512 weight slice
// (W and U halves) pinned in VGPRs. No LDS, no __syncthreads in the loop:
// h exchanged as tagged dwords through the LLC (sc0 sc1), consumers poll the
// data itself. x@W for step s overlaps the visibility latency of h_{s-1}.
// ---------------------------------------------------------------------------
__device__ __forceinline__ float fsig(float x) {
    float t = __expf(-fabsf(x));
    float r = __builtin_amdgcn_rcpf(1.0f + t);
    return x >= 0.f ? r : 1.0f - r;
}
__device__ __forceinline__ float ftanh(float x) {
    float t = __expf(-2.0f * fabsf(x));
    float r = (1.0f - t) * __builtin_amdgcn_rcpf(1.0f + t);
    return x >= 0.f ? r : -r;
}
__device__ __forceinline__ void llc_store4(unsigned* p, unsigned v) {
    asm volatile("global_store_dword %0, %1, off sc0 sc1" :: "v"(p), "v"(v) : "memory");
}

__global__ __launch_bounds__(256, 1) __attribute__((amdgpu_waves_per_eu(1, 1)))
void k_rnn(const _Float16* __restrict__ x16, const _Float16* __restrict__ wp,
           const float* __restrict__ bf, const float* __restrict__ bb,
           unsigned* __restrict__ hx, float* __restrict__ hfin)
{
    const int wg = blockIdx.x;           // 0..63 = d*32 + p*8 + grp
    const int d = wg >> 5;
    const int p = (wg >> 3) & 3;
    const int grp = wg & 7;
    const int tid = threadIdx.x;
    const int w = tid >> 6, lane = tid & 63;
    const int q = lane >> 4, l16 = lane & 15;

    // weights: wx (E half, k 0..255) + wu (H half): 64 h8 = 256 VGPRs
    h8 wx[4][8], wu[4][8];
    {
        const _Float16* bx = wp + (size_t)(d * 32 + 0  + p * 4 + w) * 16384;
        const _Float16* bu = wp + (size_t)(d * 32 + 16 + p * 4 + w) * 16384;
        #pragma unroll
        for (int nt = 0; nt < 4; ++nt)
            #pragma unroll
            for (int kb = 0; kb < 8; ++kb) {
                wx[nt][kb] = *(const h8*)(bx + nt * 4096 + l16 * 256 + kb * 32 + q * 8);
                wu[nt][kb] = *(const h8*)(bu + nt * 4096 + l16 * 256 + kb * 32 + q * 8);
            }
        // pin: make rematerialization-from-memory impossible
        #pragma unroll
        for (int nt = 0; nt < 4; ++nt)
            #pragma unroll
            for (int kb = 0; kb < 8; ++kb) {
                asm volatile("" : "+v"(wx[nt][kb]));
                asm volatile("" : "+v"(wu[nt][kb]));
            }
    }
    const float* bias = d ? bb : bf;
    float bv[4];
    #pragma unroll
    for (int g = 0; g < 4; ++g)
        bv[g] = bias[g * 256 + p * 64 + w * 16 + l16];

    unsigned* gbase = hx + (size_t)(d * 8 + grp) * 8192;  // [par 2][blk 4][row 16][unit 64]

    // x fragments for step 0
    h8 xf[8];
    {
        int xt = d ? (T_ - 1) : 0;
        const h8* xb = (const h8*)x16 + ((size_t)xt * 64 + grp * 8) * 64 + lane;
        #pragma unroll
        for (int kb = 0; kb < 8; ++kb) xf[kb] = xb[kb * 64];
    }

    float c4[4] = {0.f, 0.f, 0.f, 0.f};
    float hv4[4] = {0.f, 0.f, 0.f, 0.f};

    for (int s = 0; s < T_; ++s) {
        f4 acc[4];
        #pragma unroll
        for (int nt = 0; nt < 4; ++nt)
            acc[nt] = (f4){bv[nt], bv[nt], bv[nt], bv[nt]};
        // x @ W  (overlaps peers' h-publish visibility)
        #pragma unroll
        for (int kb = 0; kb < 8; ++kb)
            #pragma unroll
            for (int nt = 0; nt < 4; ++nt)
                acc[nt] = __builtin_amdgcn_mfma_f32_16x16x32_f16(xf[kb], wx[nt][kb], acc[nt], 0, 0, 0);

        if (s > 0) {
            const int pp = (s - 1) & 1;
            const unsigned etag = (unsigned)s << 16;
            const unsigned* pb0 = gbase + (size_t)pp * 4096 + l16 * 64 + q * 8;
            const unsigned* pb1 = pb0 + 1024;
            const unsigned* pb2 = pb0 + 2048;
            const unsigned* pb3 = pb0 + 3072;
            u4 pd[16];
            while (true) {
#define POLL_LD(i, P, OFF) asm volatile("global_load_dwordx4 %0, %1, off offset:" OFF " sc0 sc1" : "=v"(pd[i]) : "v"(P) : "memory")
                POLL_LD(0,  pb0, "0");  POLL_LD(1,  pb0, "16");
                POLL_LD(2,  pb0, "128"); POLL_LD(3,  pb0, "144");
                POLL_LD(4,  pb1, "0");  POLL_LD(5,  pb1, "16");
                POLL_LD(6,  pb1, "128"); POLL_LD(7,  pb1, "144");
                POLL_LD(8,  pb2, "0");  POLL_LD(9,  pb2, "16");
                POLL_LD(10, pb2, "128"); POLL_LD(11, pb2, "144");
                POLL_LD(12, pb3, "0");  POLL_LD(13, pb3, "16");
                POLL_LD(14, pb3, "128"); POLL_LD(15, pb3, "144");
#undef POLL_LD
                asm volatile("s_waitcnt vmcnt(0)"
                    : "+v"(pd[0]), "+v"(pd[1]), "+v"(pd[2]), "+v"(pd[3]),
                      "+v"(pd[4]), "+v"(pd[5]), "+v"(pd[6]), "+v"(pd[7]),
                      "+v"(pd[8]), "+v"(pd[9]), "+v"(pd[10]), "+v"(pd[11]),
                      "+v"(pd[12]), "+v"(pd[13]), "+v"(pd[14]), "+v"(pd[15])
                    :: "memory");
                unsigned bad = 0;
                #pragma unroll
                for (int j = 0; j < 16; ++j)
                    #pragma unroll
                    for (int e = 0; e < 4; ++e)
                        bad |= (pd[j][e] ^ etag) & 0xffff0000u;
                if (__ballot(bad != 0) == 0ull) break;
            }
            // extract h fragments (low16 of each dword) and do h @ U
            h8 hf[8];
            #pragma unroll
            for (int kb2 = 0; kb2 < 4; ++kb2)
                #pragma unroll
                for (int half = 0; half < 2; ++half) {
                    u4 a = pd[kb2 * 4 + half * 2];
                    u4 b = pd[kb2 * 4 + half * 2 + 1];
                    u4 hh;
                    hh[0] = (a[0] & 0xffffu) | (a[1] << 16);
                    hh[1] = (a[2] & 0xffffu) | (a[3] << 16);
                    hh[2] = (b[0] & 0xffffu) | (b[1] << 16);
                    hh[3] = (b[2] & 0xffffu) | (b[3] << 16);
                    hf[kb2 * 2 + half] = __builtin_bit_cast(h8, hh);
                }
            #pragma unroll
            for (int kb = 0; kb < 8; ++kb)
                #pragma unroll
                for (int nt = 0; nt < 4; ++nt)
                    acc[nt] = __builtin_amdgcn_mfma_f32_16x16x32_f16(hf[kb], wu[nt][kb], acc[nt], 0, 0, 0);
        }
        // gates
        #pragma unroll
        for (int r = 0; r < 4; ++r) {
            float zi = acc[0][r];
            float zf = acc[1][r];
            float zg = acc[2][r];
            float zo = acc[3][r];
            float cn = fsig(zf) * c4[r] + fsig(zi) * ftanh(zg);
            c4[r] = cn;
            hv4[r] = fsig(zo) * ftanh(cn);
        }
        if (s < T_ - 1) {
            // publish h_s as tagged dwords
            const unsigned otag = (unsigned)(s + 1) << 16;
            unsigned* ob = gbase + (size_t)(s & 1) * 4096 + p * 1024 + w * 16 + l16;
            #pragma unroll
            for (int r = 0; r < 4; ++r) {
                _Float16 hh = (_Float16)hv4[r];
                llc_store4(ob + (q * 4 + r) * 64,
                           otag | (unsigned)__builtin_bit_cast(unsigned short, hh));
            }
            // prefetch x fragments for step s+1 (in flight during peers' work)
            int xt = d ? (T_ - 2 - s) : (s + 1);
            const h8* xb = (const h8*)x16 + ((size_t)xt * 64 + grp * 8) * 64 + lane;
            #pragma unroll
            for (int kb = 0; kb < 8; ++kb) xf[kb] = xb[kb * 64];
        }
    }
    // final h (fp32)
    #pragma unroll
    for (int r = 0; r < 4; ++r)
        hfin[((size_t)d * B_ + grp * 16 + q * 4 + r) * H_ + p * 64 + w * 16 + l16] = hv4[r];
}

// ---------------------------------------------------------------------------
// K4: head. One block per batch row: a1 = relu([h_fwd|h_bwd] @ W1 + b1),
// logits = a1 @ W2 + b2, softmax over 32 classes. All fp32.
// ---------------------------------------------------------------------------
__global__ __launch_bounds__(256) void k_head(const float* __restrict__ hfin,
        const float* __restrict__ W1, const float* __restrict__ b1,
        const float* __restrict__ W2, const float* __restrict__ b2, float* __restrict__ out)
{
    const int b = blockIdx.x;
    const int tid = threadIdx.x;
    __shared__ float hcat[2 * H_];
    __shared__ float a1[256];
    if (tid < 128) {
        if (tid < 64)
            ((float4*)hcat)[tid] = ((const float4*)(hfin + (size_t)b * H_))[tid];
        else
            ((float4*)(hcat + H_))[tid - 64] = ((const float4*)(hfin + (size_t)(B_ + b) * H_))[tid - 64];
    }
    __syncthreads();
    {
        float s = b1[tid];
        #pragma unroll 4
        for (int k = 0; k < 2 * H_; ++k)
            s += hcat[k] * W1[(size_t)k * 256 + tid];
        a1[tid] = s > 0.f ? s : 0.f;
    }
    __syncthreads();
    if (tid < 32) {
        float s = b2[tid];
        #pragma unroll 4
        for (int j = 0; j < 256; ++j)
            s += a1[j] * W2[(size_t)j * 32 + tid];
        float mx = s;
        #pragma unroll
        for (int o = 16; o > 0; o >>= 1)
            mx = fmaxf(mx, __shfl_xor(mx, o, 32));
        float e = __expf(s - mx);
        float sum = e;
        #pragma unroll
        for (int o = 16; o > 0; o >>= 1)
            sum += __shfl_xor(sum, o, 32);
        out[(size_t)b * 32 + tid] = e / sum;
    }
}

// ---------------------------------------------------------------------------
extern "C" void kernel_launch(void* const* d_in, const int* in_sizes, int n_in,
                              void* d_out, int out_size, void* d_ws, size_t ws_size,
                              hipStream_t stream)
{
    (void)in_sizes; (void)n_in; (void)out_size; (void)ws_size;
    const int*   tok = (const int*)d_in[0];
    const float* emb = (const float*)d_in[1];
    const float* Wf  = (const float*)d_in[2];
    const float* Uf  = (const float*)d_in[3];
    const float* bf  = (const float*)d_in[4];
    const float* Wb  = (const float*)d_in[5];
    const float* Ub  = (const float*)d_in[6];
    const float* bb  = (const float*)d_in[7];
    const float* W1  = (const float*)d_in[8];
    const float* b1  = (const float*)d_in[9];
    const float* W2  = (const float*)d_in[10];
    const float* b2  = (const float*)d_in[11];
    float* out = (float*)d_out;

    char* ws = (char*)d_ws;
    _Float16* x16  = (_Float16*)(ws);                  // 33,554,432 B frag-ordered x
    _Float16* wp   = (_Float16*)(ws + 33554432);       //  2,097,152 B permuted W+U fp16
    unsigned* hx   = (unsigned*)(ws + 35651584);       //    524,288 B tagged h exchange
    float*    hfin = (float*)   (ws + 36175872);       //    262,144 B final h fp32
                                                       // total 36,438,016 B

    k_gather<<<T_, 256, 0, stream>>>(tok, emb, x16);
    k_perm  <<<64, 256, 0, stream>>>(Wf, Uf, Wb, Ub, wp);
    k_rnn   <<<64, 256, 0, stream>>>(x16, wp, bf, bb, hx, hfin);
    k_head  <<<B_, 256, 0, stream>>>(hfin, W1, b1, W2, b2, out);
}